// Round 5
// baseline (298.264 us; speedup 1.0000x reference)
//
#include <hip/hip_runtime.h>
#include <hip/hip_bf16.h>
#include <stdint.h>

// Problem constants
#define BT     32768      // B*T rows
#define CIN    512
#define NE     640        // GROUP*ENTRY
#define ENTRY  320
#define DD     256        // COUT/GROUP
#define MROWS  32         // rows per block
#define TPB    256        // 4 waves; phase1 wave = 32 rows x 160 cols

using bf16x8 = __attribute__((ext_vector_type(8))) short;
using f32x4  = __attribute__((ext_vector_type(4))) float;
using u16x8  = __attribute__((ext_vector_type(8))) unsigned short;

// LDS layout (bytes): x tile UNIONs with y (barrier-separated phases)
//   x: [0, 33280)  32 rows x 1040B (512 bf16 + 16B pad; 2-way banks on frag reads)
//   y: [0, 41472)  32 rows x 1296B (640 bf16 + pad; 2-way banks)
//   S: [41472, 41600)
#define X_STRB  1040
#define Y_STRB  1296
#define Y_STRE  648
#define S_OFF   41472
#define SMEM_BYTES 41600           // 3 blocks/CU (124.8 KB), 12 waves/CU

__device__ __forceinline__ unsigned short f2b(float f) {
    union { float f; uint32_t u; } v; v.f = f;
    uint32_t u = v.u;
    return (unsigned short)((u + 0x7FFFu + ((u >> 16) & 1u)) >> 16);
}

// Prep: Wp (fp32 [640,512]) -> WpB (bf16), codebooks (fp32 [2,320,256]) -> cbT (bf16 [2,256,320])
__global__ void prep_kernel(const float* __restrict__ Wp, const float* __restrict__ cb,
                            unsigned short* __restrict__ WpB, unsigned short* __restrict__ cbT) {
    int i = blockIdx.x * blockDim.x + threadIdx.x;
    if (i < NE * CIN) {
        WpB[i] = f2b(Wp[i]);
    } else {
        int o = i - NE * CIN;
        if (o < 2 * ENTRY * DD) {
            int g = o / (DD * ENTRY);
            int r = o - g * (DD * ENTRY);
            int d = r / ENTRY;
            int e = r - d * ENTRY;
            cbT[o] = f2b(cb[(g * ENTRY + e) * DD + d]);
        }
    }
}

__global__ __launch_bounds__(TPB, 3) void fused_kernel(
    const float* __restrict__ x, const float* __restrict__ bp,
    const float* __restrict__ gum, const unsigned short* __restrict__ WpB,
    const unsigned short* __restrict__ cbT, float* __restrict__ out) {

    extern __shared__ char smem[];
    unsigned short* yS = (unsigned short*)(smem);
    float*          sS = (float*)(smem + S_OFF);

    const int tid = threadIdx.x;
    const int w  = tid >> 6;     // wave 0..3
    const int l  = tid & 63;
    const int q  = l >> 4;       // quad 0..3
    const int ln = l & 15;
    const int rowbase = blockIdx.x * MROWS;

    if (tid < MROWS) sS[tid] = 0.0f;

    // ---- stage x tile once: 32 rows x 512 K, fp32 -> bf16 -> LDS ----
#pragma unroll
    for (int i = 0; i < 8; ++i) {
        int c   = tid + i * TPB;          // 0..2047 chunks of 8 floats
        int row = c >> 6;
        int c8  = c & 63;
        const float* p = x + (size_t)(rowbase + row) * CIN + c8 * 8;
        float4 a = *(const float4*)p;
        float4 b = *(const float4*)(p + 4);
        u16x8 hv;
        hv[0] = f2b(a.x); hv[1] = f2b(a.y); hv[2] = f2b(a.z); hv[3] = f2b(a.w);
        hv[4] = f2b(b.x); hv[5] = f2b(b.y); hv[6] = f2b(b.z); hv[7] = f2b(b.w);
        *(u16x8*)(smem + row * X_STRB + c8 * 16) = hv;
    }

    // gumbel prefetch for first phase-2 row (independent; hides HBM latency behind phase 1)
    const float* gbase = gum + (size_t)rowbase * NE + w * 160 + ln;
    float gv[10];
#pragma unroll
    for (int j = 0; j < 10; ++j) gv[j] = gbase[(size_t)(q * 4) * NE + j * 16];

    __syncthreads();   // x tile + sS visible

    // ---------------- Phase 1: logits = x @ Wp^T, B direct from global ----------------
    f32x4 acc1[2][10];
    const f32x4 fz = {0.f, 0.f, 0.f, 0.f};
#pragma unroll
    for (int rt = 0; rt < 2; ++rt)
#pragma unroll
        for (int j = 0; j < 10; ++j) acc1[rt][j] = fz;

    const unsigned short* bp1 = WpB + (size_t)(w * 160 + ln) * CIN + q * 8;

#pragma unroll 1
    for (int ks = 0; ks < 16; ++ks) {
        const int k0 = ks * 32;
        bf16x8 bc[10];
#pragma unroll
        for (int j = 0; j < 10; ++j)
            bc[j] = *(const bf16x8*)(bp1 + (size_t)j * 16 * CIN + k0);
        bf16x8 af[2];
#pragma unroll
        for (int rt = 0; rt < 2; ++rt)
            af[rt] = *(const bf16x8*)(smem + (rt * 16 + ln) * X_STRB + (k0 + q * 8) * 2);
#pragma unroll
        for (int j = 0; j < 10; ++j)
#pragma unroll
            for (int rt = 0; rt < 2; ++rt)
                acc1[rt][j] = __builtin_amdgcn_mfma_f32_16x16x32_bf16(af[rt], bc[j], acc1[rt][j], 0, 0, 0);
    }

    __syncthreads();   // all phase-1 x reads done; y may overwrite

    // ---------------- Phase 2: exp + row sums -> y LDS ----------------
    float bpv[10];
#pragma unroll
    for (int j = 0; j < 10; ++j) bpv[j] = bp[w * 160 + j * 16 + ln];

#pragma unroll
    for (int ri = 0; ri < 8; ++ri) {
        float gn[10];
        if (ri < 7) {
            int nrow = ((ri + 1) >> 2) * 16 + q * 4 + ((ri + 1) & 3);
            const float* pn = gbase + (size_t)nrow * NE;
#pragma unroll
            for (int j = 0; j < 10; ++j) gn[j] = pn[j * 16];
        }
        const int rt = ri >> 2, r = ri & 3;
        const int row = rt * 16 + q * 4 + r;
        float p = 0.f;
#pragma unroll
        for (int j = 0; j < 10; ++j) {
            float v = acc1[rt][j][r] + bpv[j] + gv[j];
            float e = __expf(v);
            yS[row * Y_STRE + w * 160 + j * 16 + ln] = f2b(e);
            p += e;
        }
        p += __shfl_xor(p, 1);
        p += __shfl_xor(p, 2);
        p += __shfl_xor(p, 4);
        p += __shfl_xor(p, 8);
        if (ln == 0) atomicAdd(&sS[row], p);
#pragma unroll
        for (int j = 0; j < 10; ++j) gv[j] = gn[j];
    }

    // ---------------- Phase 3: out = (y @ cb) / S, cb direct from global ----------------
    const int g  = w >> 1;          // group (2 waves each)
    const int nb = (w & 1) * 128;   // col block within group

    f32x4 acc2[2][8];
#pragma unroll
    for (int rt = 0; rt < 2; ++rt)
#pragma unroll
        for (int ct = 0; ct < 8; ++ct) acc2[rt][ct] = fz;

    const unsigned short* cp = cbT + (size_t)(g * DD + nb + ln) * ENTRY + q * 8;
    bf16x8 cc[8], cn[8];
#pragma unroll
    for (int ct = 0; ct < 8; ++ct) cc[ct] = *(const bf16x8*)(cp + (size_t)ct * 16 * ENTRY);

    __syncthreads();   // y writes + row-sum atomics complete

#pragma unroll 1
    for (int ks = 0; ks < 10; ++ks) {
        const int k0 = ks * 32;
        if (ks < 9) {
#pragma unroll
            for (int ct = 0; ct < 8; ++ct)
                cn[ct] = *(const bf16x8*)(cp + (size_t)ct * 16 * ENTRY + k0 + 32);
        }
        bf16x8 af2[2];
#pragma unroll
        for (int rt = 0; rt < 2; ++rt)
            af2[rt] = *(const bf16x8*)(smem + (rt * 16 + ln) * Y_STRB + (g * ENTRY + k0 + q * 8) * 2);
#pragma unroll
        for (int ct = 0; ct < 8; ++ct)
#pragma unroll
            for (int rt = 0; rt < 2; ++rt)
                acc2[rt][ct] = __builtin_amdgcn_mfma_f32_16x16x32_bf16(af2[rt], cc[ct], acc2[rt][ct], 0, 0, 0);
        if (ks < 9) {
#pragma unroll
            for (int ct = 0; ct < 8; ++ct) cc[ct] = cn[ct];
        }
    }

    // epilogue: divide by softmax denom, store fp32
#pragma unroll
    for (int rt = 0; rt < 2; ++rt) {
#pragma unroll
        for (int r = 0; r < 4; ++r) {
            const int row = rt * 16 + q * 4 + r;
            const float inv = 1.0f / sS[row];
            float* op = out + (size_t)(rowbase + row) * 512 + g * DD + nb + ln;
#pragma unroll
            for (int ct = 0; ct < 8; ++ct)
                op[ct * 16] = acc2[rt][ct][r] * inv;
        }
    }
}

extern "C" void kernel_launch(void* const* d_in, const int* in_sizes, int n_in,
                              void* d_out, int out_size, void* d_ws, size_t ws_size,
                              hipStream_t stream) {
    const float* x   = (const float*)d_in[0];
    const float* Wp  = (const float*)d_in[1];
    const float* bp  = (const float*)d_in[2];
    const float* cb  = (const float*)d_in[3];
    const float* gum = (const float*)d_in[4];
    float* out = (float*)d_out;

    unsigned short* WpB = (unsigned short*)d_ws;
    unsigned short* cbT = WpB + NE * CIN;

    int prep_total = NE * CIN + 2 * ENTRY * DD;
    prep_kernel<<<(prep_total + 255) / 256, 256, 0, stream>>>(Wp, cb, WpB, cbT);

    fused_kernel<<<dim3(BT / MROWS), dim3(TPB), SMEM_BYTES, stream>>>(x, bp, gum, WpB, cbT, out);
}

// Round 6
// 283.878 us; speedup vs baseline: 1.0507x; 1.0507x over previous
//
#include <hip/hip_runtime.h>
#include <hip/hip_bf16.h>
#include <stdint.h>

// Problem constants
#define BT     32768      // B*T rows
#define CIN    512
#define NE     640        // GROUP*ENTRY
#define ENTRY  320
#define DD     256        // COUT/GROUP
#define MROWS  64         // rows per block
#define TPB    512        // 8 waves; phase1: wave = 64 rows x 80 cols

using bf16x8 = __attribute__((ext_vector_type(8))) short;
using f32x4  = __attribute__((ext_vector_type(4))) float;
using u16x8  = __attribute__((ext_vector_type(8))) unsigned short;

// LDS layout (bytes) — x and y DISJOINT (no phase1->2 barrier)
#define X_OFF   0
#define X_STRB  1040               // 64 rows x (512 bf16 + 16B pad); 2-way banks on frag reads
#define Y_OFF   66560              // 64 rows x 1296B (640 bf16 + pad); 2-way banks
#define Y_STRB  1296
#define Y_STRE  648
#define S_OFF   149504             // 64 fp32 row sums
#define SMEM_BYTES 149760          // 1 block/CU

__device__ __forceinline__ unsigned short f2b(float f) {
    union { float f; uint32_t u; } v; v.f = f;
    uint32_t u = v.u;
    return (unsigned short)((u + 0x7FFFu + ((u >> 16) & 1u)) >> 16);
}

// Prep: Wp (fp32 [640,512]) -> WpB (bf16), codebooks (fp32 [2,320,256]) -> cbT (bf16 [2,256,320])
__global__ void prep_kernel(const float* __restrict__ Wp, const float* __restrict__ cb,
                            unsigned short* __restrict__ WpB, unsigned short* __restrict__ cbT) {
    int i = blockIdx.x * blockDim.x + threadIdx.x;
    if (i < NE * CIN) {
        WpB[i] = f2b(Wp[i]);
    } else {
        int o = i - NE * CIN;
        if (o < 2 * ENTRY * DD) {
            int g = o / (DD * ENTRY);
            int r = o - g * (DD * ENTRY);
            int d = r / ENTRY;
            int e = r - d * ENTRY;
            cbT[o] = f2b(cb[(g * ENTRY + e) * DD + d]);
        }
    }
}

__global__ __launch_bounds__(TPB, 2) void fused_kernel(
    const float* __restrict__ x, const float* __restrict__ bp,
    const float* __restrict__ gum, const unsigned short* __restrict__ WpB,
    const unsigned short* __restrict__ cbT, float* __restrict__ out) {

    extern __shared__ char smem[];
    unsigned short* yS = (unsigned short*)(smem + Y_OFF);
    float*          sS = (float*)(smem + S_OFF);

    const int tid = threadIdx.x;
    const int w  = tid >> 6;     // wave 0..7
    const int l  = tid & 63;
    const int q  = l >> 4;       // quad 0..3
    const int ln = l & 15;
    const int rowbase = blockIdx.x * MROWS;

    if (tid < MROWS) sS[tid] = 0.0f;

    // ---- stage full x tile: 64 rows x 512 K, fp32 -> bf16 -> LDS (once) ----
#pragma unroll
    for (int i = 0; i < 8; ++i) {
        int c   = tid + i * TPB;          // 0..4095 chunks of 8 floats
        int row = c >> 6;
        int c8  = c & 63;
        const float* p = x + (size_t)(rowbase + row) * CIN + c8 * 8;
        float4 a = *(const float4*)p;
        float4 b = *(const float4*)(p + 4);
        u16x8 hv;
        hv[0] = f2b(a.x); hv[1] = f2b(a.y); hv[2] = f2b(a.z); hv[3] = f2b(a.w);
        hv[4] = f2b(b.x); hv[5] = f2b(b.y); hv[6] = f2b(b.z); hv[7] = f2b(b.w);
        *(u16x8*)(smem + X_OFF + row * X_STRB + c8 * 16) = hv;
    }

    // ---- prime phase-2 gumbel: whole first 4-row batch (20 loads in flight) ----
    const float* gbase = gum + (size_t)rowbase * NE + w * 80 + ln;
    float gcur[20], gnx[20];
#pragma unroll
    for (int rr = 0; rr < 4; ++rr)
#pragma unroll
        for (int j = 0; j < 5; ++j)
            gcur[rr * 5 + j] = gbase[(size_t)(q * 4 + rr) * NE + j * 16];

    // ---------------- Phase 1: logits = x @ Wp^T, B direct from global, depth-2 ----------------
    f32x4 acc1[4][5];
    const f32x4 fz = {0.f, 0.f, 0.f, 0.f};
#pragma unroll
    for (int rt = 0; rt < 4; ++rt)
#pragma unroll
        for (int j = 0; j < 5; ++j) acc1[rt][j] = fz;

    const unsigned short* bp1 = WpB + (size_t)(w * 80 + ln) * CIN + q * 8;
    bf16x8 b0[5], b1[5], b2[5];
#pragma unroll
    for (int j = 0; j < 5; ++j) b0[j] = *(const bf16x8*)(bp1 + (size_t)j * 16 * CIN);
#pragma unroll
    for (int j = 0; j < 5; ++j) b1[j] = *(const bf16x8*)(bp1 + (size_t)j * 16 * CIN + 32);

    __syncthreads();   // x tile (and sS init) visible

#pragma unroll 1
    for (int ks = 0; ks < 16; ++ks) {
        const int k0 = ks * 32;
        if (ks < 14) {
#pragma unroll
            for (int j = 0; j < 5; ++j)
                b2[j] = *(const bf16x8*)(bp1 + (size_t)j * 16 * CIN + k0 + 64);
        }
        bf16x8 af[4];
#pragma unroll
        for (int rt = 0; rt < 4; ++rt)
            af[rt] = *(const bf16x8*)(smem + X_OFF + (rt * 16 + ln) * X_STRB + (k0 + q * 8) * 2);
#pragma unroll
        for (int j = 0; j < 5; ++j)
#pragma unroll
            for (int rt = 0; rt < 4; ++rt)
                acc1[rt][j] = __builtin_amdgcn_mfma_f32_16x16x32_bf16(af[rt], b0[j], acc1[rt][j], 0, 0, 0);
#pragma unroll
        for (int j = 0; j < 5; ++j) { b0[j] = b1[j]; b1[j] = b2[j]; }
    }

    // ---- prime phase-3 cb: first two k-slices (8 frags) before phase 2 ----
    const int g   = w >> 2;          // group (4 waves each)
    const int nbp = (w & 3) * 64;    // col block within group
    const unsigned short* cp = cbT + (size_t)(g * DD + nbp + ln) * ENTRY + q * 8;
    bf16x8 c0[4], c1[4], c2[4];
#pragma unroll
    for (int ct = 0; ct < 4; ++ct) c0[ct] = *(const bf16x8*)(cp + (size_t)ct * 16 * ENTRY);
#pragma unroll
    for (int ct = 0; ct < 4; ++ct) c1[ct] = *(const bf16x8*)(cp + (size_t)ct * 16 * ENTRY + 32);

    // ---------------- Phase 2: exp + row sums -> y LDS, 4-row batches ----------------
    float bpv[5];
#pragma unroll
    for (int j = 0; j < 5; ++j) bpv[j] = bp[w * 80 + j * 16 + ln];

#pragma unroll 1
    for (int rt = 0; rt < 4; ++rt) {
        if (rt < 3) {
#pragma unroll
            for (int rr = 0; rr < 4; ++rr)
#pragma unroll
                for (int j = 0; j < 5; ++j)
                    gnx[rr * 5 + j] = gbase[(size_t)((rt + 1) * 16 + q * 4 + rr) * NE + j * 16];
        }
#pragma unroll
        for (int rr = 0; rr < 4; ++rr) {
            const int row = rt * 16 + q * 4 + rr;
            float p = 0.f;
#pragma unroll
            for (int j = 0; j < 5; ++j) {
                float v = acc1[rt][j][rr] + bpv[j] + gcur[rr * 5 + j];
                float e = __expf(v);
                yS[row * Y_STRE + w * 80 + j * 16 + ln] = f2b(e);
                p += e;
            }
            p += __shfl_xor(p, 1);
            p += __shfl_xor(p, 2);
            p += __shfl_xor(p, 4);
            p += __shfl_xor(p, 8);
            if (ln == 0) atomicAdd(&sS[row], p);
        }
#pragma unroll
        for (int i = 0; i < 20; ++i) gcur[i] = gnx[i];
    }

    // ---------------- Phase 3: out = (y @ cb) / S, depth-2 cb prefetch ----------------
    f32x4 acc2[4][4];
#pragma unroll
    for (int rt = 0; rt < 4; ++rt)
#pragma unroll
        for (int ct = 0; ct < 4; ++ct) acc2[rt][ct] = fz;

    __syncthreads();   // all y writes + row-sum atomics complete

#pragma unroll 1
    for (int ks = 0; ks < 10; ++ks) {
        const int k0 = ks * 32;
        if (ks < 8) {
#pragma unroll
            for (int ct = 0; ct < 4; ++ct)
                c2[ct] = *(const bf16x8*)(cp + (size_t)ct * 16 * ENTRY + k0 + 64);
        }
        bf16x8 af2[4];
#pragma unroll
        for (int rt = 0; rt < 4; ++rt)
            af2[rt] = *(const bf16x8*)(smem + Y_OFF + (rt * 16 + ln) * Y_STRB + (g * ENTRY + k0 + q * 8) * 2);
#pragma unroll
        for (int ct = 0; ct < 4; ++ct)
#pragma unroll
            for (int rt = 0; rt < 4; ++rt)
                acc2[rt][ct] = __builtin_amdgcn_mfma_f32_16x16x32_bf16(af2[rt], c0[ct], acc2[rt][ct], 0, 0, 0);
#pragma unroll
        for (int ct = 0; ct < 4; ++ct) { c0[ct] = c1[ct]; c1[ct] = c2[ct]; }
    }

    // epilogue: divide by softmax denom, store fp32
#pragma unroll
    for (int rt = 0; rt < 4; ++rt) {
#pragma unroll
        for (int r = 0; r < 4; ++r) {
            const int row = rt * 16 + q * 4 + r;
            const float inv = 1.0f / sS[row];
            float* op = out + (size_t)(rowbase + row) * 512 + g * DD + nbp + ln;
#pragma unroll
            for (int ct = 0; ct < 4; ++ct)
                op[ct * 16] = acc2[rt][ct][r] * inv;
        }
    }
}

extern "C" void kernel_launch(void* const* d_in, const int* in_sizes, int n_in,
                              void* d_out, int out_size, void* d_ws, size_t ws_size,
                              hipStream_t stream) {
    const float* x   = (const float*)d_in[0];
    const float* Wp  = (const float*)d_in[1];
    const float* bp  = (const float*)d_in[2];
    const float* cb  = (const float*)d_in[3];
    const float* gum = (const float*)d_in[4];
    float* out = (float*)d_out;

    unsigned short* WpB = (unsigned short*)d_ws;
    unsigned short* cbT = WpB + NE * CIN;

    int prep_total = NE * CIN + 2 * ENTRY * DD;
    prep_kernel<<<(prep_total + 255) / 256, 256, 0, stream>>>(Wp, cb, WpB, cbT);

    fused_kernel<<<dim3(BT / MROWS), dim3(TPB), SMEM_BYTES, stream>>>(x, bp, gum, WpB, cbT, out);
}

// Round 7
// 254.218 us; speedup vs baseline: 1.1733x; 1.1167x over previous
//
#include <hip/hip_runtime.h>
#include <hip/hip_bf16.h>
#include <stdint.h>

// Problem constants
#define BT     32768      // B*T rows
#define CIN    512
#define NE     640        // GROUP*ENTRY
#define ENTRY  320
#define DD     256        // COUT/GROUP
#define MROWS  64         // rows per block
#define TPB    512        // 8 waves; phase1: wave = 64 rows x 80 cols

using bf16x8 = __attribute__((ext_vector_type(8))) short;
using f32x4  = __attribute__((ext_vector_type(4))) float;
using u16x8  = __attribute__((ext_vector_type(8))) unsigned short;

// LDS layout (bytes):
//  X region   [0, 66560)        x tile (64 x 1040B) during phase 1; y rows 0-31 (stride 1296) in phase 2/3
//  GUM-A      [66560, 107520)   gum chunks 0,2,3 (16 rows x 2560B flat)
//  Y2 region  [107520, 148992)  gum chunk 1 during phases 1-2a; y rows 32-63 (stride 1296) after
//  S          [148992, 149248)  64 fp32 row sums
#define X_STRB   1040
#define Y_STRB   1296
#define GUMA_OFF 66560
#define Y2_OFF   107520
#define S_OFF    148992
#define SMEM_BYTES 149248          // 1 block/CU

__device__ __forceinline__ unsigned short f2b(float f) {
    union { float f; uint32_t u; } v; v.f = f;
    uint32_t u = v.u;
    return (unsigned short)((u + 0x7FFFu + ((u >> 16) & 1u)) >> 16);
}

__device__ __forceinline__ void gl2lds16(const void* g, void* l) {
    __builtin_amdgcn_global_load_lds((const __attribute__((address_space(1))) void*)g,
                                     (__attribute__((address_space(3))) void*)l, 16, 0, 0);
}

// flat-copy one 16-row gumbel chunk (40960 B) into LDS: 40 x 1KB wave-instructions
__device__ __forceinline__ void stage_gum_chunk(const float* gsrc, char* lbuf, int w, int l) {
#pragma unroll
    for (int ii = 0; ii < 5; ++ii) {
        const int i = w + ii * 8;
        gl2lds16((const char*)gsrc + i * 1024 + l * 16, lbuf + i * 1024);
    }
}

// process one 16-row chunk: exp + y write + row sums. gl = LDS gum chunk, ybase = y dest for this chunk
__device__ __forceinline__ void proc_chunk(const float* gl, char* ybase, float* sS,
                                           const f32x4 (&ac)[5], const float (&bpv)[5],
                                           int srow, int w, int q, int ln) {
#pragma unroll
    for (int r = 0; r < 4; ++r) {
        const int rl = q * 4 + r;             // row within chunk
        float g5[5];
#pragma unroll
        for (int j = 0; j < 5; ++j) g5[j] = gl[rl * 640 + w * 80 + j * 16 + ln];
        float p = 0.f;
#pragma unroll
        for (int j = 0; j < 5; ++j) {
            float v = ac[j][r] + bpv[j] + g5[j];
            float e = __expf(v);
            *(unsigned short*)(ybase + rl * Y_STRB + (w * 80 + j * 16 + ln) * 2) = f2b(e);
            p += e;
        }
        p += __shfl_xor(p, 1);
        p += __shfl_xor(p, 2);
        p += __shfl_xor(p, 4);
        p += __shfl_xor(p, 8);
        if (ln == 0) atomicAdd(&sS[srow + rl], p);
    }
}

// Prep: Wp (fp32 [640,512]) -> WpB (bf16), codebooks (fp32 [2,320,256]) -> cbT (bf16 [2,256,320])
__global__ void prep_kernel(const float* __restrict__ Wp, const float* __restrict__ cb,
                            unsigned short* __restrict__ WpB, unsigned short* __restrict__ cbT) {
    int i = blockIdx.x * blockDim.x + threadIdx.x;
    if (i < NE * CIN) {
        WpB[i] = f2b(Wp[i]);
    } else {
        int o = i - NE * CIN;
        if (o < 2 * ENTRY * DD) {
            int g = o / (DD * ENTRY);
            int r = o - g * (DD * ENTRY);
            int d = r / ENTRY;
            int e = r - d * ENTRY;
            cbT[o] = f2b(cb[(g * ENTRY + e) * DD + d]);
        }
    }
}

__global__ __launch_bounds__(TPB, 2) void fused_kernel(
    const float* __restrict__ x, const float* __restrict__ bp,
    const float* __restrict__ gum, const unsigned short* __restrict__ WpB,
    const unsigned short* __restrict__ cbT, float* __restrict__ out) {

    extern __shared__ char smem[];
    float* sS = (float*)(smem + S_OFF);

    const int tid = threadIdx.x;
    const int w  = tid >> 6;     // wave 0..7
    const int l  = tid & 63;
    const int q  = l >> 4;       // quad 0..3
    const int ln = l & 15;
    const int rowbase = blockIdx.x * MROWS;

    if (tid < MROWS) sS[tid] = 0.0f;

    // ---- stage full x tile: 64 rows x 512 K, fp32 -> bf16 -> LDS (once) ----
#pragma unroll
    for (int i = 0; i < 8; ++i) {
        int c   = tid + i * TPB;          // 0..4095 chunks of 8 floats
        int row = c >> 6;
        int c8  = c & 63;
        const float* p = x + (size_t)(rowbase + row) * CIN + c8 * 8;
        float4 a = *(const float4*)p;
        float4 b = *(const float4*)(p + 4);
        u16x8 hv;
        hv[0] = f2b(a.x); hv[1] = f2b(a.y); hv[2] = f2b(a.z); hv[3] = f2b(a.w);
        hv[4] = f2b(b.x); hv[5] = f2b(b.y); hv[6] = f2b(b.z); hv[7] = f2b(b.w);
        *(u16x8*)(smem + row * X_STRB + c8 * 16) = hv;
    }

    // ---------------- Phase 1: logits = x @ Wp^T, B direct from global (R4) ----------------
    f32x4 acc1[4][5];
    const f32x4 fz = {0.f, 0.f, 0.f, 0.f};
#pragma unroll
    for (int rt = 0; rt < 4; ++rt)
#pragma unroll
        for (int j = 0; j < 5; ++j) acc1[rt][j] = fz;

    const unsigned short* bp1 = WpB + (size_t)(w * 80 + ln) * CIN + q * 8;
    bf16x8 bc[5], bn[5];
#pragma unroll
    for (int j = 0; j < 5; ++j) bc[j] = *(const bf16x8*)(bp1 + (size_t)j * 16 * CIN);

    __syncthreads();   // x tile + sS visible

    // async gum chunks 0,1 -> GUM-A, Y2 (hidden under the whole K-loop; drained at B0)
    stage_gum_chunk(gum + (size_t)(rowbase +  0) * NE, smem + GUMA_OFF, w, l);
    stage_gum_chunk(gum + (size_t)(rowbase + 16) * NE, smem + Y2_OFF,   w, l);

#pragma unroll 1
    for (int ks = 0; ks < 16; ++ks) {
        const int k0 = ks * 32;
        if (ks < 15) {
#pragma unroll
            for (int j = 0; j < 5; ++j)
                bn[j] = *(const bf16x8*)(bp1 + (size_t)j * 16 * CIN + k0 + 32);
        }
        bf16x8 af[4];
#pragma unroll
        for (int rt = 0; rt < 4; ++rt)
            af[rt] = *(const bf16x8*)(smem + (rt * 16 + ln) * X_STRB + (k0 + q * 8) * 2);
#pragma unroll
        for (int j = 0; j < 5; ++j)
#pragma unroll
            for (int rt = 0; rt < 4; ++rt)
                acc1[rt][j] = __builtin_amdgcn_mfma_f32_16x16x32_bf16(af[rt], bc[j], acc1[rt][j], 0, 0, 0);
#pragma unroll
        for (int j = 0; j < 5; ++j) bc[j] = bn[j];
    }

    // ---------------- Phase 2: exp + row sums, gum from LDS chunks ----------------
    float bpv[5];
#pragma unroll
    for (int j = 0; j < 5; ++j) bpv[j] = bp[w * 80 + j * 16 + ln];

    __syncthreads();   // B0: x reads done; chunks 0,1 resident

    // chunk 0 (rows 0-15): gum A, y -> X region
    proc_chunk((const float*)(smem + GUMA_OFF), smem, sS, acc1[0], bpv, 0, w, q, ln);
    __syncthreads();   // B1: chunk-0 reads done
    stage_gum_chunk(gum + (size_t)(rowbase + 32) * NE, smem + GUMA_OFF, w, l);   // chunk 2 -> A (in flight)
    // chunk 1 (rows 16-31): gum Y2, y -> X region
    proc_chunk((const float*)(smem + Y2_OFF), smem + 16 * Y_STRB, sS, acc1[1], bpv, 16, w, q, ln);
    __syncthreads();   // B2: drains chunk 2; Y2 reads done
    // chunk 2 (rows 32-47): gum A, y -> Y2[0,20736)
    proc_chunk((const float*)(smem + GUMA_OFF), smem + Y2_OFF, sS, acc1[2], bpv, 32, w, q, ln);
    __syncthreads();   // B3: chunk-2 reads done
    stage_gum_chunk(gum + (size_t)(rowbase + 48) * NE, smem + GUMA_OFF, w, l);   // chunk 3 -> A

    // prime phase-3 cb frags while chunk 3 is in flight
    const int g   = w >> 2;          // group (4 waves each)
    const int nbp = (w & 3) * 64;    // col block within group
    const unsigned short* cp = cbT + (size_t)(g * DD + nbp + ln) * ENTRY + q * 8;
    bf16x8 cc[4], cn[4];
#pragma unroll
    for (int ct = 0; ct < 4; ++ct) cc[ct] = *(const bf16x8*)(cp + (size_t)ct * 16 * ENTRY);

    __syncthreads();   // B4: drain chunk 3 (the one exposed latency)
    // chunk 3 (rows 48-63): gum A, y -> Y2[20736,41472)
    proc_chunk((const float*)(smem + GUMA_OFF), smem + Y2_OFF + 16 * Y_STRB, sS, acc1[3], bpv, 48, w, q, ln);

    // ---------------- Phase 3: out = (y @ cb) / S, cb direct from global (R4) ----------------
    f32x4 acc2[4][4];
#pragma unroll
    for (int rt = 0; rt < 4; ++rt)
#pragma unroll
        for (int ct = 0; ct < 4; ++ct) acc2[rt][ct] = fz;

    __syncthreads();   // B5: all y writes + row-sum atomics complete

#pragma unroll 1
    for (int ks = 0; ks < 10; ++ks) {
        const int k0 = ks * 32;
        if (ks < 9) {
#pragma unroll
            for (int ct = 0; ct < 4; ++ct)
                cn[ct] = *(const bf16x8*)(cp + (size_t)ct * 16 * ENTRY + k0 + 32);
        }
        const int coff = (g * ENTRY + k0 + q * 8) * 2;
        bf16x8 af2[4];
        af2[0] = *(const bf16x8*)(smem + (ln)      * Y_STRB + coff);
        af2[1] = *(const bf16x8*)(smem + (16 + ln) * Y_STRB + coff);
        af2[2] = *(const bf16x8*)(smem + Y2_OFF + (ln)      * Y_STRB + coff);
        af2[3] = *(const bf16x8*)(smem + Y2_OFF + (16 + ln) * Y_STRB + coff);
#pragma unroll
        for (int ct = 0; ct < 4; ++ct)
#pragma unroll
            for (int rt = 0; rt < 4; ++rt)
                acc2[rt][ct] = __builtin_amdgcn_mfma_f32_16x16x32_bf16(af2[rt], cc[ct], acc2[rt][ct], 0, 0, 0);
#pragma unroll
        for (int ct = 0; ct < 4; ++ct) cc[ct] = cn[ct];
    }

    // epilogue: divide by softmax denom, store fp32
#pragma unroll
    for (int rt = 0; rt < 4; ++rt) {
#pragma unroll
        for (int r = 0; r < 4; ++r) {
            const int row = rt * 16 + q * 4 + r;
            const float inv = 1.0f / sS[row];
            float* op = out + (size_t)(rowbase + row) * 512 + g * DD + nbp + ln;
#pragma unroll
            for (int ct = 0; ct < 4; ++ct)
                op[ct * 16] = acc2[rt][ct][r] * inv;
        }
    }
}

extern "C" void kernel_launch(void* const* d_in, const int* in_sizes, int n_in,
                              void* d_out, int out_size, void* d_ws, size_t ws_size,
                              hipStream_t stream) {
    const float* x   = (const float*)d_in[0];
    const float* Wp  = (const float*)d_in[1];
    const float* bp  = (const float*)d_in[2];
    const float* cb  = (const float*)d_in[3];
    const float* gum = (const float*)d_in[4];
    float* out = (float*)d_out;

    unsigned short* WpB = (unsigned short*)d_ws;
    unsigned short* cbT = WpB + NE * CIN;

    int prep_total = NE * CIN + 2 * ENTRY * DD;
    prep_kernel<<<(prep_total + 255) / 256, 256, 0, stream>>>(Wp, cb, WpB, cbT);

    fused_kernel<<<dim3(BT / MROWS), dim3(TPB), SMEM_BYTES, stream>>>(x, bp, gum, WpB, cbT, out);
}